// Round 12
// baseline (245.998 us; speedup 1.0000x reference)
//
#include <hip/hip_runtime.h>
#include <hip/hip_bf16.h>
#include <hip/hip_fp16.h>

typedef __attribute__((ext_vector_type(8))) short short8;
typedef __attribute__((ext_vector_type(8))) _Float16 f16x8;
typedef __attribute__((ext_vector_type(2))) _Float16 f16x2;
typedef __attribute__((ext_vector_type(4))) float f32x4;
typedef __attribute__((ext_vector_type(4))) unsigned int u32x4;
typedef unsigned short u16;
typedef unsigned int u32;

constexpr int CB = 4, CN = 2048, CF = 128, CD = 64, CH = 4;
constexpr int IT = 32;   // i-rows per attn block

__device__ inline u32 fmap(float f) {
    u32 b = __float_as_uint(f);
    return b ^ ((u32)(((int)b) >> 31) | 0x80000000u);
}
__device__ inline float funmap(u32 u) {
    u32 b = (u & 0x80000000u) ? (u ^ 0x80000000u) : ~u;
    return __uint_as_float(b);
}
__device__ inline u16 bf16bits(float v) {
    __hip_bfloat16 b = __float2bfloat16(v);
    return *reinterpret_cast<u16*>(&b);
}

// ---------------------------------------------------------------------------
// Kernel 0: fused prep (unchanged from R11).
// ---------------------------------------------------------------------------
__global__ __launch_bounds__(256) void prep_k(const int* __restrict__ A,
                                              const float* __restrict__ W,
                                              u32* __restrict__ mask,
                                              u32* __restrict__ smax_u,
                                              u16* __restrict__ WThi,
                                              u16* __restrict__ WTlo) {
    int blk = blockIdx.x, t = threadIdx.x;
    if (blk < 16384) {
        int gid = blk * 256 + t;
        if (blk == 0 && t < CH * CB) smax_u[t] = 0u;  // ~ -inf under fmap
        unsigned long long mk = __ballot(A[gid] > 0);
        if ((t & 63) == 0) {
            mask[gid >> 5] = (u32)mk;
            mask[(gid >> 5) + 1] = (u32)(mk >> 32);
        }
    } else {
        int idx = (blk - 16384) * 256 + t;   // 0..32767
        int e = idx & 7;
        int l = (idx >> 3) & 63;
        int dt = (idx >> 9) & 3;
        int kk = (idx >> 11) & 3;
        int h = idx >> 13;
        int f = kk * 32 + (l >> 4) * 8 + e;
        int d = dt * 16 + (l & 15);
        float v = W[(h * CF + f) * CD + d];
        __hip_bfloat16 bh = __float2bfloat16(v);
        WThi[idx] = *reinterpret_cast<u16*>(&bh);
        WTlo[idx] = bf16bits(v - __bfloat162float(bh));
    }
}

// ---------------------------------------------------------------------------
// Kernel 1: MFMA projection (unchanged from R11).
// ---------------------------------------------------------------------------
__global__ __launch_bounds__(256, 2) void proj_k(const float* __restrict__ X,
                                                 const u16* __restrict__ WThi,
                                                 const u16* __restrict__ WTlo,
                                                 const float* __restrict__ AK,
                                                 u16* __restrict__ hT,
                                                 float* __restrict__ sout,
                                                 u16* __restrict__ eout,
                                                 u32* __restrict__ smax_u) {
    __shared__ float tr[4][CD][17];

    int blk = blockIdx.x;             // b*128 + ntile
    int ntile = blk & 127;
    int b = blk >> 7;
    int n0 = ntile * 16;
    int t = threadIdx.x;
    int w = t >> 6, l = t & 63;
    int h = w;
    int row_l = l & 15, jg = l >> 4;

    const float* xrow = X + ((size_t)b * CN + n0 + row_l) * CF + jg * 8;
    const short8* whiU = reinterpret_cast<const short8*>(WThi) + (size_t)h * 1024 + l;
    const short8* wloU = reinterpret_cast<const short8*>(WTlo) + (size_t)h * 1024 + l;

    float4 xa[4], xb[4];
#pragma unroll
    for (int kk = 0; kk < 4; ++kk) {
        xa[kk] = *reinterpret_cast<const float4*>(xrow + kk * 32);
        xb[kk] = *reinterpret_cast<const float4*>(xrow + kk * 32 + 4);
    }
    short8 bhi[4][4], blo[4][4];
#pragma unroll
    for (int kk = 0; kk < 4; ++kk)
#pragma unroll
        for (int dt = 0; dt < 4; ++dt) {
            bhi[kk][dt] = whiU[(kk * 4 + dt) * 64];
            blo[kk][dt] = wloU[(kk * 4 + dt) * 64];
        }

    f32x4 c[4];
    f32x4 zero = {0.f, 0.f, 0.f, 0.f};
#pragma unroll
    for (int dt = 0; dt < 4; ++dt) c[dt] = zero;

#pragma unroll
    for (int kk = 0; kk < 4; ++kk) {
        float xv[8] = {xa[kk].x, xa[kk].y, xa[kk].z, xa[kk].w,
                       xb[kk].x, xb[kk].y, xb[kk].z, xb[kk].w};
        short8 ahi, alo;
#pragma unroll
        for (int e = 0; e < 8; ++e) {
            __hip_bfloat16 bh = __float2bfloat16(xv[e]);
            ahi[e] = (short)*reinterpret_cast<u16*>(&bh);
            alo[e] = (short)bf16bits(xv[e] - __bfloat162float(bh));
        }
#pragma unroll
        for (int dt = 0; dt < 4; ++dt) {
            c[dt] = __builtin_amdgcn_mfma_f32_16x16x32_bf16(ahi, bhi[kk][dt], c[dt], 0, 0, 0);
            c[dt] = __builtin_amdgcn_mfma_f32_16x16x32_bf16(ahi, blo[kk][dt], c[dt], 0, 0, 0);
            c[dt] = __builtin_amdgcn_mfma_f32_16x16x32_bf16(alo, bhi[kk][dt], c[dt], 0, 0, 0);
        }
    }

    float av[4];
#pragma unroll
    for (int dt = 0; dt < 4; ++dt) av[dt] = AK[h * CD + dt * 16 + row_l];
    float sacc[4];
#pragma unroll
    for (int r = 0; r < 4; ++r)
        sacc[r] = c[0][r] * av[0] + c[1][r] * av[1] + c[2][r] * av[2] + c[3][r] * av[3];
#pragma unroll
    for (int off = 1; off <= 8; off <<= 1)
#pragma unroll
        for (int r = 0; r < 4; ++r) sacc[r] += __shfl_xor(sacc[r], off, 64);

    float mx = fmaxf(fmaxf(sacc[0], sacc[1]), fmaxf(sacc[2], sacc[3]));
    mx = fmaxf(mx, __shfl_xor(mx, 16, 64));
    mx = fmaxf(mx, __shfl_xor(mx, 32, 64));
    if (l == 0) atomicMax(&smax_u[h * CB + b], fmap(mx));

    if (row_l == 0) {
#pragma unroll
        for (int r = 0; r < 4; ++r) {
            size_t si = (size_t)(h * CB + b) * CN + n0 + jg * 4 + r;
            sout[si] = sacc[r];
            _Float16 ev = (_Float16)__expf(sacc[r]);
            eout[si] = *reinterpret_cast<u16*>(&ev);
        }
    }

#pragma unroll
    for (int dt = 0; dt < 4; ++dt)
#pragma unroll
        for (int r = 0; r < 4; ++r) tr[w][dt * 16 + row_l][jg * 4 + r] = c[dt][r];
    __syncthreads();

    f16x8* hTs = reinterpret_cast<f16x8*>(hT);
    int jc = l >> 5, d0 = l & 31;
#pragma unroll
    for (int half = 0; half < 2; ++half) {
        f16x8 pk;
#pragma unroll
        for (int e = 0; e < 8; ++e)
            pk[e] = (_Float16)tr[w][half * 32 + d0][jc * 8 + e];
        hTs[((size_t)(h * CB + b) * 256 + ntile * 2 + jc) * 64 + half * 32 + d0] = pk;
    }
}

// ---------------------------------------------------------------------------
// Kernel 2: flash PV partials. Grid 512 = (b, 32-row tile, K-half of 1024);
// 1024 thr = 16 waves = (head hq, K-quarter jq of 256 = 8 kk). XCD-swizzled.
// E + mask preloaded into REGISTERS; fully-unrolled 8-step loop touches no
// LDS and no barriers. LDS only for cbuf cross-wave reduce (71.6 KB) ->
// 2 blocks/CU, 8 waves/SIMD. Partials (num per head, den) -> global.
// ---------------------------------------------------------------------------
__global__ __launch_bounds__(1024, 8) void attn_k(const u16* __restrict__ hT,
                                                  const float* __restrict__ s_ws,
                                                  const u32* __restrict__ e_ws32,
                                                  const u32* __restrict__ smax_u,
                                                  const u32* __restrict__ mask32,
                                                  float* __restrict__ numC,
                                                  float* __restrict__ denC) {
    __shared__ float cbuf[CH][2][IT][68];        // 69.6 KB
    __shared__ float lbuf[CH][4][IT];            // 2 KB

    int blk = blockIdx.x;
    int xcd = blk & 7, pos = blk >> 3;     // round-robin XCD assignment
    int b = xcd >> 1;                      // 2 XCDs per b
    int it = (xcd & 1) * 32 + (pos >> 1);  // tile 0..63
    int kh = pos & 1;                      // K-half
    int i0 = it * IT;
    int t = threadIdx.x, w = t >> 6, l = t & 63;
    int hq = w >> 2, jq = w & 3;
    int row_l = l & 15, jg = l >> 4;

    // ---- register preloads (no LDS staging) ----
    const u32* mrow0 = mask32 + (size_t)(i0 + row_l) * 64 + kh * 32 + jq * 8;
    const u32* mrow1 = mask32 + (size_t)(i0 + 16 + row_l) * 64 + kh * 32 + jq * 8;
    u32x4 mw0a = *reinterpret_cast<const u32x4*>(mrow0);
    u32x4 mw0b = *reinterpret_cast<const u32x4*>(mrow0 + 4);
    u32x4 mw1a = *reinterpret_cast<const u32x4*>(mrow1);
    u32x4 mw1b = *reinterpret_cast<const u32x4*>(mrow1 + 4);

    const u32* ebase = e_ws32 + (size_t)(hq * CB + b) * 1024 + kh * 512 + jq * 128 + jg * 4;
    u32x4 ew0 = *reinterpret_cast<const u32x4*>(ebase + 0 * 16);
    u32x4 ew1 = *reinterpret_cast<const u32x4*>(ebase + 1 * 16);
    u32x4 ew2 = *reinterpret_cast<const u32x4*>(ebase + 2 * 16);
    u32x4 ew3 = *reinterpret_cast<const u32x4*>(ebase + 3 * 16);
    u32x4 ew4 = *reinterpret_cast<const u32x4*>(ebase + 4 * 16);
    u32x4 ew5 = *reinterpret_cast<const u32x4*>(ebase + 5 * 16);
    u32x4 ew6 = *reinterpret_cast<const u32x4*>(ebase + 6 * 16);
    u32x4 ew7 = *reinterpret_cast<const u32x4*>(ebase + 7 * 16);

    float smax = funmap(smax_u[hq * CB + b]);
    float si0 = s_ws[(size_t)(hq * CB + b) * CN + i0 + row_l];
    float si1 = s_ws[(size_t)(hq * CB + b) * CN + i0 + 16 + row_l];
    float m0 = fmaxf(si0 + smax, 0.f), m1 = fmaxf(si1 + smax, 0.f);
    _Float16 ei0s = (_Float16)__expf(si0 - m0), ci0s = (_Float16)__expf(-m0);
    _Float16 ei1s = (_Float16)__expf(si1 - m1), ci1s = (_Float16)__expf(-m1);
    f16x2 Ei0 = {ei0s, ei0s}, Ci0 = {ci0s, ci0s};
    f16x2 Ei1 = {ei1s, ei1s}, Ci1 = {ci1s, ci1s};

    f32x4 c0[4], c1[4], cl0, cl1;
    f32x4 zero = {0.f, 0.f, 0.f, 0.f};
#pragma unroll
    for (int dt = 0; dt < 4; ++dt) { c0[dt] = zero; c1[dt] = zero; }
    cl0 = zero; cl1 = zero;

    f16x8 ones;
#pragma unroll
    for (int e = 0; e < 8; ++e) ones[e] = (_Float16)1.0f;

    // B pointer: unit[(hb*256 + kh*128 + jq*32 + kk*4 + jg)*64 + dt*16 + row_l]
    const f16x8* hp = reinterpret_cast<const f16x8*>(hT) +
                      ((size_t)(hq * CB + b) * 256 + kh * 128 + jq * 32 + jg) * 64 + row_l;

    f16x8 bfA[4], bfB[4];
#pragma unroll
    for (int dt = 0; dt < 4; ++dt) bfA[dt] = hp[dt * 16];

#define ATTN_STEP(KK, BCUR, BNXT, KNXT, EW, BY0EXPR, BY1EXPR)                    \
    do {                                                                         \
        _Pragma("unroll") for (int dt = 0; dt < 4; ++dt)                         \
            BNXT[dt] = hp[(KNXT) * 256 + dt * 16];                               \
        u32 by0 = (BY0EXPR) >> (jg * 8);                                         \
        u32 by1 = (BY1EXPR) >> (jg * 8);                                         \
        u32x4 af0w, af1w;                                                        \
        _Pragma("unroll") for (int p = 0; p < 4; ++p) {                          \
            u32 ewv = (EW)[p];                                                   \
            f16x2 e2 = __builtin_bit_cast(f16x2, ewv);                           \
            f16x2 t0 = __builtin_elementwise_max(Ei0 * e2, Ci0);                 \
            f16x2 t1 = __builtin_elementwise_max(Ei1 * e2, Ci1);                 \
            u32 mk0 = (((by0 >> (2 * p)) & 1u) ? 0xFFFFu : 0u) |                 \
                      (((by0 >> (2 * p + 1)) & 1u) ? 0xFFFF0000u : 0u);          \
            u32 mk1 = (((by1 >> (2 * p)) & 1u) ? 0xFFFFu : 0u) |                 \
                      (((by1 >> (2 * p + 1)) & 1u) ? 0xFFFF0000u : 0u);          \
            af0w[p] = __builtin_bit_cast(u32, t0) & mk0;                         \
            af1w[p] = __builtin_bit_cast(u32, t1) & mk1;                         \
        }                                                                        \
        f16x8 af0 = __builtin_bit_cast(f16x8, af0w);                             \
        f16x8 af1 = __builtin_bit_cast(f16x8, af1w);                             \
        __builtin_amdgcn_s_setprio(1);                                           \
        _Pragma("unroll") for (int dt = 0; dt < 4; ++dt) {                       \
            c0[dt] = __builtin_amdgcn_mfma_f32_16x16x32_f16(af0, BCUR[dt], c0[dt], 0, 0, 0); \
            c1[dt] = __builtin_amdgcn_mfma_f32_16x16x32_f16(af1, BCUR[dt], c1[dt], 0, 0, 0); \
        }                                                                        \
        cl0 = __builtin_amdgcn_mfma_f32_16x16x32_f16(af0, ones, cl0, 0, 0, 0);   \
        cl1 = __builtin_amdgcn_mfma_f32_16x16x32_f16(af1, ones, cl1, 0, 0, 0);   \
        __builtin_amdgcn_s_setprio(0);                                           \
    } while (0)

    ATTN_STEP(0, bfA, bfB, 1, ew0, mw0a[0], mw1a[0]);
    ATTN_STEP(1, bfB, bfA, 2, ew1, mw0a[1], mw1a[1]);
    ATTN_STEP(2, bfA, bfB, 3, ew2, mw0a[2], mw1a[2]);
    ATTN_STEP(3, bfB, bfA, 4, ew3, mw0a[3], mw1a[3]);
    ATTN_STEP(4, bfA, bfB, 5, ew4, mw0b[0], mw1b[0]);
    ATTN_STEP(5, bfB, bfA, 6, ew5, mw0b[1], mw1b[1]);
    ATTN_STEP(6, bfA, bfB, 7, ew6, mw0b[2], mw1b[2]);
    ATTN_STEP(7, bfB, bfA, 7, ew7, mw0b[3], mw1b[3]);
#undef ATTN_STEP

    // ---- cross-wave reduction over K-quarters (2 LDS slots) ----
    // C/D layout: col = lane&15, row = (lane>>4)*4 + reg
    int slot = jq & 1;
    if (row_l == 0)
#pragma unroll
        for (int r = 0; r < 4; ++r) {
            lbuf[hq][jq][jg * 4 + r] = cl0[r];
            lbuf[hq][jq][16 + jg * 4 + r] = cl1[r];
        }
    if (jq < 2) {
#pragma unroll
        for (int dt = 0; dt < 4; ++dt)
#pragma unroll
            for (int r = 0; r < 4; ++r) {
                cbuf[hq][slot][jg * 4 + r][dt * 16 + row_l] = c0[dt][r];
                cbuf[hq][slot][16 + jg * 4 + r][dt * 16 + row_l] = c1[dt][r];
            }
    }
    __syncthreads();
    if (jq >= 2) {
#pragma unroll
        for (int dt = 0; dt < 4; ++dt)
#pragma unroll
            for (int r = 0; r < 4; ++r) {
                cbuf[hq][slot][jg * 4 + r][dt * 16 + row_l] += c0[dt][r];
                cbuf[hq][slot][16 + jg * 4 + r][dt * 16 + row_l] += c1[dt][r];
            }
    }
    __syncthreads();

    // ---- write per-(block) partials: num[h][row][d], den[h][row] ----
    size_t base = (size_t)(b * 64 + it) * 2 + kh;
    for (int idx = t; idx < CH * IT * CD; idx += 1024) {
        int h = idx >> 11, row = (idx >> 6) & 31, d = idx & 63;
        numC[((base * CH + h) * IT + row) * CD + d] =
            cbuf[h][0][row][d] + cbuf[h][1][row][d];
    }
    if (t < CH * IT) {
        int h = t >> 5, row = t & 31;
        denC[(base * CH + h) * IT + row] =
            lbuf[h][0][row] + lbuf[h][1][row] + lbuf[h][2][row] + lbuf[h][3][row];
    }
}

// ---------------------------------------------------------------------------
// Kernel 3: combine K-halves, divide, head-mean, leaky relu.
// ---------------------------------------------------------------------------
__global__ __launch_bounds__(256) void combine_k(const float* __restrict__ numC,
                                                 const float* __restrict__ denC,
                                                 float* __restrict__ out) {
    int idx = blockIdx.x * 256 + threadIdx.x;   // [b][i][d] flat
    int d = idx & 63;
    int i = (idx >> 6) & 2047;
    int b = idx >> 17;
    int it = i >> 5, row = i & 31;
    size_t b0 = (size_t)(b * 64 + it) * 2;
    float acc = 0.f;
#pragma unroll
    for (int h = 0; h < CH; ++h) {
        float num = numC[((b0 * CH + h) * IT + row) * CD + d] +
                    numC[(((b0 + 1) * CH + h) * IT + row) * CD + d];
        float den = denC[(b0 * CH + h) * IT + row] +
                    denC[((b0 + 1) * CH + h) * IT + row];
        acc += num / fmaxf(den, 1e-30f);
    }
    float o = acc * 0.25f;
    out[idx] = o > 0.f ? o : 0.2f * o;
}

// ---------------------------------------------------------------------------
extern "C" void kernel_launch(void* const* d_in, const int* in_sizes, int n_in,
                              void* d_out, int out_size, void* d_ws, size_t ws_size,
                              hipStream_t stream) {
    const float* X  = (const float*)d_in[0];   // [B,N,F]
    const int*   A  = (const int*)d_in[1];     // [N,N]
    const float* W  = (const float*)d_in[2];   // [H,F,D]
    const float* AK = (const float*)d_in[3];   // [H,D]
    float* out = (float*)d_out;                // [B,N,D]

    char* wp = (char*)d_ws;
    float* s_ws = (float*)wp;    wp += 131072;     // 16*2048 f32
    u16* e_ws = (u16*)wp;        wp += 131072;     // 16*2048 f16 (64KB used)
    u32* smax_ws = (u32*)wp;     wp += 256;
    u32* mask_ws = (u32*)wp;     wp += 524288;     // 2048*64 u32
    u16* hT = (u16*)wp;          wp += 4194304;    // 16*256*64 f16x8 units
    u16* WThi = (u16*)wp;        wp += 65536;      // fragment-major bf16
    u16* WTlo = (u16*)wp;        wp += 65536;
    float* numC = (float*)wp;    wp += 16777216;   // 512 blk * 4h * 32 * 64 f32
    float* denC = (float*)wp;    wp += 262144;     // 512 blk * 4h * 32 f32

    prep_k<<<16384 + 128, 256, 0, stream>>>(A, W, mask_ws, smax_ws, WThi, WTlo);
    proj_k<<<CB * (CN / 16), 256, 0, stream>>>(X, WThi, WTlo, AK, hT, s_ws, e_ws, smax_ws);
    attn_k<<<512, 1024, 0, stream>>>(hT, s_ws, (const u32*)e_ws,
                                     smax_ws, mask_ws, numC, denC);
    combine_k<<<CB * CN * CD / 256, 256, 0, stream>>>(numC, denC, out);
}

// Round 16
// 83.598 us; speedup vs baseline: 2.9426x; 2.9426x over previous
//
#include <hip/hip_runtime.h>
#include <hip/hip_bf16.h>
#include <hip/hip_fp16.h>

typedef __attribute__((ext_vector_type(8))) short short8;
typedef __attribute__((ext_vector_type(8))) _Float16 f16x8;
typedef __attribute__((ext_vector_type(2))) _Float16 f16x2;
typedef __attribute__((ext_vector_type(4))) float f32x4;
typedef __attribute__((ext_vector_type(4))) unsigned int u32x4;
typedef unsigned short u16;
typedef unsigned int u32;

constexpr int CB = 4, CN = 2048, CF = 128, CD = 64, CH = 4;
constexpr int IT = 32;   // i-rows per attn block

__device__ inline u32 fmap(float f) {
    u32 b = __float_as_uint(f);
    return b ^ ((u32)(((int)b) >> 31) | 0x80000000u);
}
__device__ inline float funmap(u32 u) {
    u32 b = (u & 0x80000000u) ? (u ^ 0x80000000u) : ~u;
    return __uint_as_float(b);
}
__device__ inline u16 bf16bits(float v) {
    __hip_bfloat16 b = __float2bfloat16(v);
    return *reinterpret_cast<u16*>(&b);
}

// ---------------------------------------------------------------------------
// Kernel 1: projection + inline W-convert + (h==0 blocks) mask pack.
// block = (b, h, 4 consecutive 16-row tiles); 4 waves = 4 sub-tiles, same
// head -> W[h] staged once in LDS (32 KB f32). Split-bf16 MFMA:
// Xhi*Whi + Xhi*Wlo + Xlo*Whi (same values as R11's prep+proj pipeline).
// Outputs: hT f16 (d-major 16B units), s f32, E=exp(s) f16, smax atomicMax
// (smax_u zero-initialized by hipMemsetAsync before this kernel).
// h==0 blocks ballot-pack 16 rows of A each into mask_ws.
// ---------------------------------------------------------------------------
__global__ __launch_bounds__(256, 4) void proj_k(const float* __restrict__ X,
                                                 const int* __restrict__ A,
                                                 const float* __restrict__ W,
                                                 const float* __restrict__ AK,
                                                 u16* __restrict__ hT,
                                                 float* __restrict__ sout,
                                                 u16* __restrict__ eout,
                                                 u32* __restrict__ smax_u,
                                                 u32* __restrict__ mask_ws) {
    __shared__ float wbuf[CF * CD];   // 32 KB: W[h] f32
    __shared__ float tr[4][CD][17];   // 17.4 KB transpose staging

    int blk = blockIdx.x;             // b*128 + h*32 + tile4
    int b = blk >> 7;
    int h = (blk >> 5) & 3;
    int tile4 = blk & 31;
    int t = threadIdx.x, w = t >> 6, l = t & 63;
    int row_l = l & 15, jg = l >> 4;
    int n0 = tile4 * 64 + w * 16;

    // ---- mask pack (h==0 blocks): rows [tile4*64 + b*16, +16) ----
    if (h == 0) {
        int rowbase = tile4 * 64 + b * 16;
        for (int iter = 0; iter < 128; ++iter) {
            int idx = iter * 256 + t;
            int rl2 = idx >> 11, col = idx & 2047;
            unsigned long long mk = __ballot(A[(size_t)(rowbase + rl2) * CN + col] > 0);
            if (l == 0) {
                mask_ws[(rowbase + rl2) * 64 + (col >> 5)] = (u32)mk;
                mask_ws[(rowbase + rl2) * 64 + (col >> 5) + 1] = (u32)(mk >> 32);
            }
        }
    }

    // ---- stage W[h] ----
    for (int idx = t; idx < CF * CD; idx += 256) wbuf[idx] = W[(size_t)h * CF * CD + idx];
    __syncthreads();

    // ---- X loads (hoisted) ----
    const float* xrow = X + ((size_t)b * CN + n0 + row_l) * CF + jg * 8;
    float4 xa[4], xb[4];
#pragma unroll
    for (int kk = 0; kk < 4; ++kk) {
        xa[kk] = *reinterpret_cast<const float4*>(xrow + kk * 32);
        xb[kk] = *reinterpret_cast<const float4*>(xrow + kk * 32 + 4);
    }

    f32x4 c[4];
    f32x4 zero = {0.f, 0.f, 0.f, 0.f};
#pragma unroll
    for (int dt = 0; dt < 4; ++dt) c[dt] = zero;

#pragma unroll
    for (int kk = 0; kk < 4; ++kk) {
        float xv[8] = {xa[kk].x, xa[kk].y, xa[kk].z, xa[kk].w,
                       xb[kk].x, xb[kk].y, xb[kk].z, xb[kk].w};
        short8 ahi, alo;
#pragma unroll
        for (int e = 0; e < 8; ++e) {
            __hip_bfloat16 bh = __float2bfloat16(xv[e]);
            ahi[e] = (short)*reinterpret_cast<u16*>(&bh);
            alo[e] = (short)bf16bits(xv[e] - __bfloat162float(bh));
        }
#pragma unroll
        for (int dt = 0; dt < 4; ++dt) {
            short8 bhi, blo;
#pragma unroll
            for (int e = 0; e < 8; ++e) {
                float v = wbuf[(kk * 32 + jg * 8 + e) * CD + dt * 16 + row_l];
                __hip_bfloat16 bh = __float2bfloat16(v);
                bhi[e] = (short)*reinterpret_cast<u16*>(&bh);
                blo[e] = (short)bf16bits(v - __bfloat162float(bh));
            }
            c[dt] = __builtin_amdgcn_mfma_f32_16x16x32_bf16(ahi, bhi, c[dt], 0, 0, 0);
            c[dt] = __builtin_amdgcn_mfma_f32_16x16x32_bf16(ahi, blo, c[dt], 0, 0, 0);
            c[dt] = __builtin_amdgcn_mfma_f32_16x16x32_bf16(alo, bhi, c[dt], 0, 0, 0);
        }
    }

    // ---- s = h . a ----
    float av[4];
#pragma unroll
    for (int dt = 0; dt < 4; ++dt) av[dt] = AK[h * CD + dt * 16 + row_l];
    float sacc[4];
#pragma unroll
    for (int r = 0; r < 4; ++r)
        sacc[r] = c[0][r] * av[0] + c[1][r] * av[1] + c[2][r] * av[2] + c[3][r] * av[3];
#pragma unroll
    for (int off = 1; off <= 8; off <<= 1)
#pragma unroll
        for (int r = 0; r < 4; ++r) sacc[r] += __shfl_xor(sacc[r], off, 64);

    float mx = fmaxf(fmaxf(sacc[0], sacc[1]), fmaxf(sacc[2], sacc[3]));
    mx = fmaxf(mx, __shfl_xor(mx, 16, 64));
    mx = fmaxf(mx, __shfl_xor(mx, 32, 64));
    if (l == 0) atomicMax(&smax_u[h * CB + b], fmap(mx));

    if (row_l == 0) {
#pragma unroll
        for (int r = 0; r < 4; ++r) {
            size_t si = (size_t)(h * CB + b) * CN + n0 + jg * 4 + r;
            sout[si] = sacc[r];
            _Float16 ev = (_Float16)__expf(sacc[r]);
            eout[si] = *reinterpret_cast<u16*>(&ev);
        }
    }

    // ---- transpose to hT (f16) via LDS; coalesced 16B stores ----
#pragma unroll
    for (int dt = 0; dt < 4; ++dt)
#pragma unroll
        for (int r = 0; r < 4; ++r) tr[w][dt * 16 + row_l][jg * 4 + r] = c[dt][r];
    __syncthreads();

    f16x8* hTs = reinterpret_cast<f16x8*>(hT);
    int ntile = tile4 * 4 + w;
    int jc = l >> 5, d0 = l & 31;
#pragma unroll
    for (int half = 0; half < 2; ++half) {
        f16x8 pk;
#pragma unroll
        for (int e = 0; e < 8; ++e)
            pk[e] = (_Float16)tr[w][half * 32 + d0][jc * 8 + e];
        hTs[((size_t)(h * CB + b) * 256 + ntile * 2 + jc) * 64 + half * 32 + d0] = pk;
    }
}

// ---------------------------------------------------------------------------
// Kernel 2: fused flash PV + head-mean + leaky (VERBATIM R11 — known pass).
// 1024 thr = 16 waves = (head hq, K-quarter jq of 512), grid 256,
// XCD-swizzled. Weight pair = max(Ei2*e2, Ci2) & maskword; denominator =
// ones-MFMA of SAME f16 weights. Depth-1 B prefetch, setprio, unroll-1.
// ---------------------------------------------------------------------------
__global__ __launch_bounds__(1024, 4) void attn_k(const u16* __restrict__ hT,
                                                  const float* __restrict__ s_ws,
                                                  const u32* __restrict__ e_ws32,
                                                  const u32* __restrict__ smax_u,
                                                  const u32* __restrict__ mask32,
                                                  float* __restrict__ out) {
    __shared__ alignas(16) u32 e_sl[CH][CN / 2];  // 16 KB (f16 pairs)
    __shared__ u32 m_lds[IT][65];                 // 8.3 KB
    __shared__ float cbuf[CH][2][IT][68];         // 69.6 KB
    __shared__ float lbuf[CH][4][IT];             // 2 KB

    int orig = blockIdx.x;
    int xcd = orig & 7, pos = orig >> 3;   // round-robin XCD assignment
    int b = xcd >> 1;                      // 2 XCDs per b
    int it = (xcd & 1) * 32 + pos;         // tile 0..63
    int i0 = it * IT;
    int t = threadIdx.x, w = t >> 6, l = t & 63;
    int hq = w >> 2, jq = w & 3;
    int row_l = l & 15, jg = l >> 4;

    for (int idx = t; idx < CH * (CN / 2); idx += 1024) {
        int hh = idx >> 10, j = idx & 1023;
        e_sl[hh][j] = e_ws32[(size_t)(hh * CB + b) * (CN / 2) + j];
    }
    for (int idx = t; idx < IT * 64; idx += 1024) {
        int r = idx >> 6, wd = idx & 63;
        m_lds[r][wd] = mask32[(size_t)(i0 + r) * 64 + wd];
    }
    __syncthreads();

    float smax = funmap(smax_u[hq * CB + b]);
    float si0 = s_ws[(size_t)(hq * CB + b) * CN + i0 + row_l];
    float si1 = s_ws[(size_t)(hq * CB + b) * CN + i0 + 16 + row_l];
    float m0 = fmaxf(si0 + smax, 0.f), m1 = fmaxf(si1 + smax, 0.f);
    _Float16 ei0s = (_Float16)__expf(si0 - m0), ci0s = (_Float16)__expf(-m0);
    _Float16 ei1s = (_Float16)__expf(si1 - m1), ci1s = (_Float16)__expf(-m1);
    f16x2 Ei0 = {ei0s, ei0s}, Ci0 = {ci0s, ci0s};
    f16x2 Ei1 = {ei1s, ei1s}, Ci1 = {ci1s, ci1s};

    f32x4 c0[4], c1[4], cl0, cl1;
    f32x4 zero = {0.f, 0.f, 0.f, 0.f};
#pragma unroll
    for (int dt = 0; dt < 4; ++dt) { c0[dt] = zero; c1[dt] = zero; }
    cl0 = zero; cl1 = zero;

    f16x8 ones;
#pragma unroll
    for (int e = 0; e < 8; ++e) ones[e] = (_Float16)1.0f;

    // B pointer: unit[(hb*256 + jq*64 + kk*4 + jg)*64 + dt*16 + row_l]
    const f16x8* hp = reinterpret_cast<const f16x8*>(hT) +
                      ((size_t)(hq * CB + b) * 256 + jq * 64 + jg) * 64 + row_l;

    f16x8 bfA[4], bfB[4];
#pragma unroll
    for (int dt = 0; dt < 4; ++dt) bfA[dt] = hp[dt * 16];

#define ATTN_STEP(KK, BCUR, BNXT, KNXT)                                          \
    do {                                                                         \
        _Pragma("unroll") for (int dt = 0; dt < 4; ++dt)                         \
            BNXT[dt] = hp[(KNXT) * 256 + dt * 16];                               \
        int jw = jq * 256 + (KK) * 16 + jg * 4;                                  \
        u32x4 ejw = *reinterpret_cast<const u32x4*>(&e_sl[hq][jw]);              \
        u32 by0 = m_lds[row_l][jq * 16 + (KK)] >> (jg * 8);                      \
        u32 by1 = m_lds[16 + row_l][jq * 16 + (KK)] >> (jg * 8);                 \
        u32x4 af0w, af1w;                                                        \
        _Pragma("unroll") for (int p = 0; p < 4; ++p) {                          \
            u32 ewv = ejw[p];                                                    \
            f16x2 e2 = __builtin_bit_cast(f16x2, ewv);                           \
            f16x2 t0 = __builtin_elementwise_max(Ei0 * e2, Ci0);                 \
            f16x2 t1 = __builtin_elementwise_max(Ei1 * e2, Ci1);                 \
            u32 mk0 = (((by0 >> (2 * p)) & 1u) ? 0xFFFFu : 0u) |                 \
                      (((by0 >> (2 * p + 1)) & 1u) ? 0xFFFF0000u : 0u);          \
            u32 mk1 = (((by1 >> (2 * p)) & 1u) ? 0xFFFFu : 0u) |                 \
                      (((by1 >> (2 * p + 1)) & 1u) ? 0xFFFF0000u : 0u);          \
            af0w[p] = __builtin_bit_cast(u32, t0) & mk0;                         \
            af1w[p] = __builtin_bit_cast(u32, t1) & mk1;                         \
        }                                                                        \
        f16x8 af0 = __builtin_bit_cast(f16x8, af0w);                             \
        f16x8 af1 = __builtin_bit_cast(f16x8, af1w);                             \
        __builtin_amdgcn_s_setprio(1);                                           \
        _Pragma("unroll") for (int dt = 0; dt < 4; ++dt) {                       \
            c0[dt] = __builtin_amdgcn_mfma_f32_16x16x32_f16(af0, BCUR[dt], c0[dt], 0, 0, 0); \
            c1[dt] = __builtin_amdgcn_mfma_f32_16x16x32_f16(af1, BCUR[dt], c1[dt], 0, 0, 0); \
        }                                                                        \
        cl0 = __builtin_amdgcn_mfma_f32_16x16x32_f16(af0, ones, cl0, 0, 0, 0);   \
        cl1 = __builtin_amdgcn_mfma_f32_16x16x32_f16(af1, ones, cl1, 0, 0, 0);   \
        __builtin_amdgcn_s_setprio(0);                                           \
    } while (0)

#pragma unroll 1
    for (int kp = 0; kp < 16; kp += 2) {
        ATTN_STEP(kp, bfA, bfB, kp + 1);
        int kn = (kp + 2 < 16) ? kp + 2 : 15;
        ATTN_STEP(kp + 1, bfB, bfA, kn);
    }
#undef ATTN_STEP

    // ---- cross-wave reduction over K-quarters (2 LDS slots) ----
    // C/D layout: col = lane&15, row = (lane>>4)*4 + reg
    int slot = jq & 1;
    if (row_l == 0)
#pragma unroll
        for (int r = 0; r < 4; ++r) {
            lbuf[hq][jq][jg * 4 + r] = cl0[r];
            lbuf[hq][jq][16 + jg * 4 + r] = cl1[r];
        }
    if (jq < 2) {
#pragma unroll
        for (int dt = 0; dt < 4; ++dt)
#pragma unroll
            for (int r = 0; r < 4; ++r) {
                cbuf[hq][slot][jg * 4 + r][dt * 16 + row_l] = c0[dt][r];
                cbuf[hq][slot][16 + jg * 4 + r][dt * 16 + row_l] = c1[dt][r];
            }
    }
    __syncthreads();
    if (jq >= 2) {
#pragma unroll
        for (int dt = 0; dt < 4; ++dt)
#pragma unroll
            for (int r = 0; r < 4; ++r) {
                cbuf[hq][slot][jg * 4 + r][dt * 16 + row_l] += c0[dt][r];
                cbuf[hq][slot][16 + jg * 4 + r][dt * 16 + row_l] += c1[dt][r];
            }
    }
    __syncthreads();

    // ---- epilogue: slot-sum, divide, head-mean, leaky, store ----
    for (int idx = t; idx < IT * CD; idx += 1024) {
        int row = idx >> 6, d = idx & 63;
        float acc = 0.f;
#pragma unroll
        for (int h = 0; h < CH; ++h) {
            float num = cbuf[h][0][row][d] + cbuf[h][1][row][d];
            float den = lbuf[h][0][row] + lbuf[h][1][row] + lbuf[h][2][row] + lbuf[h][3][row];
            acc += num / fmaxf(den, 1e-30f);
        }
        float o = acc * 0.25f;
        out[((size_t)b * CN + i0 + row) * CD + d] = o > 0.f ? o : 0.2f * o;
    }
}

// ---------------------------------------------------------------------------
extern "C" void kernel_launch(void* const* d_in, const int* in_sizes, int n_in,
                              void* d_out, int out_size, void* d_ws, size_t ws_size,
                              hipStream_t stream) {
    const float* X  = (const float*)d_in[0];   // [B,N,F]
    const int*   A  = (const int*)d_in[1];     // [N,N]
    const float* W  = (const float*)d_in[2];   // [H,F,D]
    const float* AK = (const float*)d_in[3];   // [H,D]
    float* out = (float*)d_out;                // [B,N,D]

    char* wp = (char*)d_ws;
    float* s_ws = (float*)wp;    wp += 131072;     // 16*2048 f32
    u16* e_ws = (u16*)wp;        wp += 131072;     // 16*2048 f16 (64KB used)
    u32* smax_ws = (u32*)wp;     wp += 256;
    u32* mask_ws = (u32*)wp;     wp += 524288;     // 2048*64 u32
    u16* hT = (u16*)wp;          wp += 4194304;    // 16*256*64 f16x8 units

    hipMemsetAsync(smax_ws, 0, 256, stream);       // smax identity under fmap
    proj_k<<<CB * CH * 32, 256, 0, stream>>>(X, A, W, AK, hT, s_ws, e_ws,
                                             smax_ws, mask_ws);
    attn_k<<<CB * (CN / IT), 1024, 0, stream>>>(hT, s_ws, (const u32*)e_ws,
                                                smax_ws, mask_ws, out);
}

// Round 17
// 62.337 us; speedup vs baseline: 3.9463x; 1.3411x over previous
//
#include <hip/hip_runtime.h>
#include <hip/hip_bf16.h>
#include <hip/hip_fp16.h>

typedef __attribute__((ext_vector_type(8))) short short8;
typedef __attribute__((ext_vector_type(8))) _Float16 f16x8;
typedef __attribute__((ext_vector_type(2))) _Float16 f16x2;
typedef __attribute__((ext_vector_type(4))) float f32x4;
typedef __attribute__((ext_vector_type(4))) unsigned int u32x4;
typedef unsigned short u16;
typedef unsigned int u32;

constexpr int CB = 4, CN = 2048, CF = 128, CD = 64, CH = 4;
constexpr int IT = 32;   // i-rows per attn block

__device__ inline u32 fmap(float f) {
    u32 b = __float_as_uint(f);
    return b ^ ((u32)(((int)b) >> 31) | 0x80000000u);
}
__device__ inline float funmap(u32 u) {
    u32 b = (u & 0x80000000u) ? (u ^ 0x80000000u) : ~u;
    return __uint_as_float(b);
}
__device__ inline u16 bf16bits(float v) {
    __hip_bfloat16 b = __float2bfloat16(v);
    return *reinterpret_cast<u16*>(&b);
}

// ---------------------------------------------------------------------------
// Kernel 1: projection + inline W-convert + DISTRIBUTED mask pack.
// block = (b, h, 4 consecutive 16-row tiles); 4 waves = 4 sub-tiles, same
// head. W[h] staged TRANSPOSED+PADDED in LDS ([64][132] f32 -> <=2-way bank
// conflicts on fragment reads). Every block packs 4 adjacency rows
// (unrolled x4 -> independent ballots in flight). Same numerics as R16.
// ---------------------------------------------------------------------------
__global__ __launch_bounds__(256, 2) void proj_k(const float* __restrict__ X,
                                                 const int* __restrict__ A,
                                                 const float* __restrict__ W,
                                                 const float* __restrict__ AK,
                                                 u16* __restrict__ hT,
                                                 float* __restrict__ sout,
                                                 u16* __restrict__ eout,
                                                 u32* __restrict__ smax_u,
                                                 u32* __restrict__ mask_ws) {
    __shared__ float wbuf[CD][CF + 4];   // 33.8 KB: W[h] f32, [d][f] padded
    __shared__ float tr[4][CD][17];      // 17.4 KB transpose staging

    int blk = blockIdx.x;             // b*128 + h*32 + tile4
    int b = blk >> 7;
    int h = (blk >> 5) & 3;
    int tile4 = blk & 31;
    int t = threadIdx.x, w = t >> 6, l = t & 63;
    int row_l = l & 15, jg = l >> 4;
    int n0 = tile4 * 64 + w * 16;

    // ---- stage W[h] transposed ([d][f], padded) ----
    for (int idx = t; idx < CF * CD; idx += 256)
        wbuf[idx & 63][idx >> 6] = W[(size_t)h * CF * CD + idx];

    // ---- mask pack: every block packs rows [blk*4, blk*4+4) ----
    {
        int rowbase = blk * 4;
#pragma unroll 4
        for (int iter = 0; iter < 32; ++iter) {
            int idx = iter * 256 + t;              // 0..8191
            int rl2 = idx >> 11, col = idx & 2047;
            unsigned long long mk = __ballot(A[(size_t)(rowbase + rl2) * CN + col] > 0);
            if (l == 0) {
                mask_ws[(rowbase + rl2) * 64 + (col >> 5)] = (u32)mk;
                mask_ws[(rowbase + rl2) * 64 + (col >> 5) + 1] = (u32)(mk >> 32);
            }
        }
    }
    __syncthreads();

    // ---- X loads (hoisted) ----
    const float* xrow = X + ((size_t)b * CN + n0 + row_l) * CF + jg * 8;
    float4 xa[4], xb[4];
#pragma unroll
    for (int kk = 0; kk < 4; ++kk) {
        xa[kk] = *reinterpret_cast<const float4*>(xrow + kk * 32);
        xb[kk] = *reinterpret_cast<const float4*>(xrow + kk * 32 + 4);
    }

    f32x4 c[4];
    f32x4 zero = {0.f, 0.f, 0.f, 0.f};
#pragma unroll
    for (int dt = 0; dt < 4; ++dt) c[dt] = zero;

#pragma unroll
    for (int kk = 0; kk < 4; ++kk) {
        float xv[8] = {xa[kk].x, xa[kk].y, xa[kk].z, xa[kk].w,
                       xb[kk].x, xb[kk].y, xb[kk].z, xb[kk].w};
        short8 ahi, alo;
#pragma unroll
        for (int e = 0; e < 8; ++e) {
            __hip_bfloat16 bh = __float2bfloat16(xv[e]);
            ahi[e] = (short)*reinterpret_cast<u16*>(&bh);
            alo[e] = (short)bf16bits(xv[e] - __bfloat162float(bh));
        }
#pragma unroll
        for (int dt = 0; dt < 4; ++dt) {
            short8 bhi, blo;
#pragma unroll
            for (int e = 0; e < 8; ++e) {
                float v = wbuf[dt * 16 + row_l][kk * 32 + jg * 8 + e];
                __hip_bfloat16 bh = __float2bfloat16(v);
                bhi[e] = (short)*reinterpret_cast<u16*>(&bh);
                blo[e] = (short)bf16bits(v - __bfloat162float(bh));
            }
            c[dt] = __builtin_amdgcn_mfma_f32_16x16x32_bf16(ahi, bhi, c[dt], 0, 0, 0);
            c[dt] = __builtin_amdgcn_mfma_f32_16x16x32_bf16(ahi, blo, c[dt], 0, 0, 0);
            c[dt] = __builtin_amdgcn_mfma_f32_16x16x32_bf16(alo, bhi, c[dt], 0, 0, 0);
        }
    }

    // ---- s = h . a ----
    float av[4];
#pragma unroll
    for (int dt = 0; dt < 4; ++dt) av[dt] = AK[h * CD + dt * 16 + row_l];
    float sacc[4];
#pragma unroll
    for (int r = 0; r < 4; ++r)
        sacc[r] = c[0][r] * av[0] + c[1][r] * av[1] + c[2][r] * av[2] + c[3][r] * av[3];
#pragma unroll
    for (int off = 1; off <= 8; off <<= 1)
#pragma unroll
        for (int r = 0; r < 4; ++r) sacc[r] += __shfl_xor(sacc[r], off, 64);

    float mx = fmaxf(fmaxf(sacc[0], sacc[1]), fmaxf(sacc[2], sacc[3]));
    mx = fmaxf(mx, __shfl_xor(mx, 16, 64));
    mx = fmaxf(mx, __shfl_xor(mx, 32, 64));
    if (l == 0) atomicMax(&smax_u[h * CB + b], fmap(mx));

    if (row_l == 0) {
#pragma unroll
        for (int r = 0; r < 4; ++r) {
            size_t si = (size_t)(h * CB + b) * CN + n0 + jg * 4 + r;
            sout[si] = sacc[r];
            _Float16 ev = (_Float16)__expf(sacc[r]);
            eout[si] = *reinterpret_cast<u16*>(&ev);
        }
    }

    // ---- transpose to hT (f16) via LDS; coalesced 16B stores ----
#pragma unroll
    for (int dt = 0; dt < 4; ++dt)
#pragma unroll
        for (int r = 0; r < 4; ++r) tr[w][dt * 16 + row_l][jg * 4 + r] = c[dt][r];
    __syncthreads();

    f16x8* hTs = reinterpret_cast<f16x8*>(hT);
    int ntile = tile4 * 4 + w;
    int jc = l >> 5, d0 = l & 31;
#pragma unroll
    for (int half = 0; half < 2; ++half) {
        f16x8 pk;
#pragma unroll
        for (int e = 0; e < 8; ++e)
            pk[e] = (_Float16)tr[w][half * 32 + d0][jc * 8 + e];
        hTs[((size_t)(h * CB + b) * 256 + ntile * 2 + jc) * 64 + half * 32 + d0] = pk;
    }
}

// ---------------------------------------------------------------------------
// Kernel 2: fused flash PV + head-mean + leaky (VERBATIM R11/R16 — passes).
// ---------------------------------------------------------------------------
__global__ __launch_bounds__(1024, 4) void attn_k(const u16* __restrict__ hT,
                                                  const float* __restrict__ s_ws,
                                                  const u32* __restrict__ e_ws32,
                                                  const u32* __restrict__ smax_u,
                                                  const u32* __restrict__ mask32,
                                                  float* __restrict__ out) {
    __shared__ alignas(16) u32 e_sl[CH][CN / 2];  // 16 KB (f16 pairs)
    __shared__ u32 m_lds[IT][65];                 // 8.3 KB
    __shared__ float cbuf[CH][2][IT][68];         // 69.6 KB
    __shared__ float lbuf[CH][4][IT];             // 2 KB

    int orig = blockIdx.x;
    int xcd = orig & 7, pos = orig >> 3;   // round-robin XCD assignment
    int b = xcd >> 1;                      // 2 XCDs per b
    int it = (xcd & 1) * 32 + pos;         // tile 0..63
    int i0 = it * IT;
    int t = threadIdx.x, w = t >> 6, l = t & 63;
    int hq = w >> 2, jq = w & 3;
    int row_l = l & 15, jg = l >> 4;

    for (int idx = t; idx < CH * (CN / 2); idx += 1024) {
        int hh = idx >> 10, j = idx & 1023;
        e_sl[hh][j] = e_ws32[(size_t)(hh * CB + b) * (CN / 2) + j];
    }
    for (int idx = t; idx < IT * 64; idx += 1024) {
        int r = idx >> 6, wd = idx & 63;
        m_lds[r][wd] = mask32[(size_t)(i0 + r) * 64 + wd];
    }
    __syncthreads();

    float smax = funmap(smax_u[hq * CB + b]);
    float si0 = s_ws[(size_t)(hq * CB + b) * CN + i0 + row_l];
    float si1 = s_ws[(size_t)(hq * CB + b) * CN + i0 + 16 + row_l];
    float m0 = fmaxf(si0 + smax, 0.f), m1 = fmaxf(si1 + smax, 0.f);
    _Float16 ei0s = (_Float16)__expf(si0 - m0), ci0s = (_Float16)__expf(-m0);
    _Float16 ei1s = (_Float16)__expf(si1 - m1), ci1s = (_Float16)__expf(-m1);
    f16x2 Ei0 = {ei0s, ei0s}, Ci0 = {ci0s, ci0s};
    f16x2 Ei1 = {ei1s, ei1s}, Ci1 = {ci1s, ci1s};

    f32x4 c0[4], c1[4], cl0, cl1;
    f32x4 zero = {0.f, 0.f, 0.f, 0.f};
#pragma unroll
    for (int dt = 0; dt < 4; ++dt) { c0[dt] = zero; c1[dt] = zero; }
    cl0 = zero; cl1 = zero;

    f16x8 ones;
#pragma unroll
    for (int e = 0; e < 8; ++e) ones[e] = (_Float16)1.0f;

    // B pointer: unit[(hb*256 + jq*64 + kk*4 + jg)*64 + dt*16 + row_l]
    const f16x8* hp = reinterpret_cast<const f16x8*>(hT) +
                      ((size_t)(hq * CB + b) * 256 + jq * 64 + jg) * 64 + row_l;

    f16x8 bfA[4], bfB[4];
#pragma unroll
    for (int dt = 0; dt < 4; ++dt) bfA[dt] = hp[dt * 16];

#define ATTN_STEP(KK, BCUR, BNXT, KNXT)                                          \
    do {                                                                         \
        _Pragma("unroll") for (int dt = 0; dt < 4; ++dt)                         \
            BNXT[dt] = hp[(KNXT) * 256 + dt * 16];                               \
        int jw = jq * 256 + (KK) * 16 + jg * 4;                                  \
        u32x4 ejw = *reinterpret_cast<const u32x4*>(&e_sl[hq][jw]);              \
        u32 by0 = m_lds[row_l][jq * 16 + (KK)] >> (jg * 8);                      \
        u32 by1 = m_lds[16 + row_l][jq * 16 + (KK)] >> (jg * 8);                 \
        u32x4 af0w, af1w;                                                        \
        _Pragma("unroll") for (int p = 0; p < 4; ++p) {                          \
            u32 ewv = ejw[p];                                                    \
            f16x2 e2 = __builtin_bit_cast(f16x2, ewv);                           \
            f16x2 t0 = __builtin_elementwise_max(Ei0 * e2, Ci0);                 \
            f16x2 t1 = __builtin_elementwise_max(Ei1 * e2, Ci1);                 \
            u32 mk0 = (((by0 >> (2 * p)) & 1u) ? 0xFFFFu : 0u) |                 \
                      (((by0 >> (2 * p + 1)) & 1u) ? 0xFFFF0000u : 0u);          \
            u32 mk1 = (((by1 >> (2 * p)) & 1u) ? 0xFFFFu : 0u) |                 \
                      (((by1 >> (2 * p + 1)) & 1u) ? 0xFFFF0000u : 0u);          \
            af0w[p] = __builtin_bit_cast(u32, t0) & mk0;                         \
            af1w[p] = __builtin_bit_cast(u32, t1) & mk1;                         \
        }                                                                        \
        f16x8 af0 = __builtin_bit_cast(f16x8, af0w);                             \
        f16x8 af1 = __builtin_bit_cast(f16x8, af1w);                             \
        __builtin_amdgcn_s_setprio(1);                                           \
        _Pragma("unroll") for (int dt = 0; dt < 4; ++dt) {                       \
            c0[dt] = __builtin_amdgcn_mfma_f32_16x16x32_f16(af0, BCUR[dt], c0[dt], 0, 0, 0); \
            c1[dt] = __builtin_amdgcn_mfma_f32_16x16x32_f16(af1, BCUR[dt], c1[dt], 0, 0, 0); \
        }                                                                        \
        cl0 = __builtin_amdgcn_mfma_f32_16x16x32_f16(af0, ones, cl0, 0, 0, 0);   \
        cl1 = __builtin_amdgcn_mfma_f32_16x16x32_f16(af1, ones, cl1, 0, 0, 0);   \
        __builtin_amdgcn_s_setprio(0);                                           \
    } while (0)

#pragma unroll 1
    for (int kp = 0; kp < 16; kp += 2) {
        ATTN_STEP(kp, bfA, bfB, kp + 1);
        int kn = (kp + 2 < 16) ? kp + 2 : 15;
        ATTN_STEP(kp + 1, bfB, bfA, kn);
    }
#undef ATTN_STEP

    // ---- cross-wave reduction over K-quarters (2 LDS slots) ----
    // C/D layout: col = lane&15, row = (lane>>4)*4 + reg
    int slot = jq & 1;
    if (row_l == 0)
#pragma unroll
        for (int r = 0; r < 4; ++r) {
            lbuf[hq][jq][jg * 4 + r] = cl0[r];
            lbuf[hq][jq][16 + jg * 4 + r] = cl1[r];
        }
    if (jq < 2) {
#pragma unroll
        for (int dt = 0; dt < 4; ++dt)
#pragma unroll
            for (int r = 0; r < 4; ++r) {
                cbuf[hq][slot][jg * 4 + r][dt * 16 + row_l] = c0[dt][r];
                cbuf[hq][slot][16 + jg * 4 + r][dt * 16 + row_l] = c1[dt][r];
            }
    }
    __syncthreads();
    if (jq >= 2) {
#pragma unroll
        for (int dt = 0; dt < 4; ++dt)
#pragma unroll
            for (int r = 0; r < 4; ++r) {
                cbuf[hq][slot][jg * 4 + r][dt * 16 + row_l] += c0[dt][r];
                cbuf[hq][slot][16 + jg * 4 + r][dt * 16 + row_l] += c1[dt][r];
            }
    }
    __syncthreads();

    // ---- epilogue: slot-sum, divide, head-mean, leaky, store ----
    for (int idx = t; idx < IT * CD; idx += 1024) {
        int row = idx >> 6, d = idx & 63;
        float acc = 0.f;
#pragma unroll
        for (int h = 0; h < CH; ++h) {
            float num = cbuf[h][0][row][d] + cbuf[h][1][row][d];
            float den = lbuf[h][0][row] + lbuf[h][1][row] + lbuf[h][2][row] + lbuf[h][3][row];
            acc += num / fmaxf(den, 1e-30f);
        }
        float o = acc * 0.25f;
        out[((size_t)b * CN + i0 + row) * CD + d] = o > 0.f ? o : 0.2f * o;
    }
}

// ---------------------------------------------------------------------------
extern "C" void kernel_launch(void* const* d_in, const int* in_sizes, int n_in,
                              void* d_out, int out_size, void* d_ws, size_t ws_size,
                              hipStream_t stream) {
    const float* X  = (const float*)d_in[0];   // [B,N,F]
    const int*   A  = (const int*)d_in[1];     // [N,N]
    const float* W  = (const float*)d_in[2];   // [H,F,D]
    const float* AK = (const float*)d_in[3];   // [H,D]
    float* out = (float*)d_out;                // [B,N,D]

    char* wp = (char*)d_ws;
    float* s_ws = (float*)wp;    wp += 131072;     // 16*2048 f32
    u16* e_ws = (u16*)wp;        wp += 131072;     // 16*2048 f16 (64KB used)
    u32* smax_ws = (u32*)wp;     wp += 256;
    u32* mask_ws = (u32*)wp;     wp += 524288;     // 2048*64 u32
    u16* hT = (u16*)wp;          wp += 4194304;    // 16*256*64 f16x8 units

    hipMemsetAsync(smax_ws, 0, 256, stream);       // smax identity under fmap
    proj_k<<<CB * CH * 32, 256, 0, stream>>>(X, A, W, AK, hT, s_ws, e_ws,
                                             smax_ws, mask_ws);
    attn_k<<<CB * (CN / IT), 1024, 0, stream>>>(hT, s_ws, (const u32*)e_ws,
                                                smax_ws, mask_ws, out);
}